// Round 4
// baseline (192.210 us; speedup 1.0000x reference)
//
#include <hip/hip_runtime.h>
#include <math.h>

// Problem constants (from reference setup_inputs)
#define BS 64      // batch
#define F  256     // features (K of the Gram matmul)
#define M  128     // columns  (M=N of the Gram matmul)
#define NPAIRS 2080  // 64*65/2 pairs a<=b; S(b,a)=S(a,b)^T -> identical histogram

typedef unsigned short u16;
typedef _Float16 f16x8 __attribute__((ext_vector_type(8)));
typedef float    f32x16 __attribute__((ext_vector_type(16)));

// ---------------------------------------------------------------------------
// Pre-pass: fp32 -> fp16 (RNE) + transpose [f][m] -> [m][f], via LDS so both
// global read and global write are coalesced. (verified rounds 2-3; absmax
// 0.0039 with single-pass fp16.)
// Grid: (128 = mat*64+b, 4 = f-chunk of 64).
// ---------------------------------------------------------------------------
__global__ __launch_bounds__(256) void convert_f16_kernel(
    const float* __restrict__ m1, const float* __restrict__ m2,
    u16* __restrict__ hT)
{
    __shared__ float tile[64 * M];   // [f-chunk 64][m 128], 32 KB
    const int mat = blockIdx.x >> 6;
    const int b   = blockIdx.x & 63;
    const int f0  = blockIdx.y * 64;
    const float* src = (mat == 0 ? m1 : m2) + (size_t)b * (F * M) + (size_t)f0 * M;
    const size_t obase = (size_t)(mat * BS + b) * M * F;
    const int tid = threadIdx.x;

    const float4* g = (const float4*)src;
    float4* s = (float4*)tile;
    #pragma unroll
    for (int i = 0; i < 8; ++i)
        s[tid + i * 256] = g[tid + i * 256];
    __syncthreads();

    const int m  = tid >> 1;
    const int fb = (tid & 1) * 8;
    #pragma unroll
    for (int pass = 0; pass < 4; ++pass) {
        const int fs = fb + pass * 16;
        u16 hh[8] __attribute__((aligned(16)));
        #pragma unroll
        for (int j = 0; j < 8; ++j) {
            const float x = tile[(fs + j) * M + m];   // 2 lanes/bank -> free
            const _Float16 h = (_Float16)x;           // RNE
            hh[j] = __builtin_bit_cast(u16, h);
        }
        *(uint4*)&hT[obase + (size_t)m * F + f0 + fs] = *(const uint4*)hh;
    }
}

// ---------------------------------------------------------------------------
// One block per (pair, input). 4 waves in 2x2; each wave a 64x64 C-region =
// 2x2 mfma_f32_32x32x16_f16 tiles. NO LDS staging: operands are L2-hot
// (8.4 MB working set) and already fragment-laid-out, so each lane loads its
// 16B fragment straight from global. K-loop has zero barriers; compiler
// interleaves MFMA with global_load via fine-grained vmcnt (AITER pattern).
// Operand addressing identical to the LDS version verified in rounds 2-3:
// lane&31 -> row within 32-tile, lane>>5 -> 8-wide k-granule.
// ---------------------------------------------------------------------------
__global__ __launch_bounds__(256, 4) void gram_hist_mfma(
    const u16* __restrict__ hT, float* __restrict__ out)
{
    __shared__ int   hist[8];
    __shared__ float sred[8];

    const int tid  = threadIdx.x;
    const int lane = tid & 63;
    const int w    = tid >> 6;

    if (tid < 8) hist[tid] = 0;

    // Decode pair blockIdx.x -> (a, b), a <= b (uniform scalar loop).
    int p = blockIdx.x, a = 0;
    { int cnt = BS; while (p >= cnt) { p -= cnt; ++a; --cnt; } }
    const int b = a + p;
    const int mat = blockIdx.y;

    const u16* Ag = hT + (size_t)(mat * BS + a) * M * F;
    const u16* Bg = hT + (size_t)(mat * BS + b) * M * F;

    const int wr = (w >> 1) * 64;       // wave row-band base
    const int wc = (w & 1) * 64;        // wave col-band base
    const int l31   = lane & 31;
    const int lhalf = lane >> 5;

    // Per-lane fragment base pointers (16B-aligned: row*512B + lhalf*16B).
    const u16* pa0 = Ag + (size_t)(wr      + l31) * F + lhalf * 8;
    const u16* pa1 = Ag + (size_t)(wr + 32 + l31) * F + lhalf * 8;
    const u16* pb0 = Bg + (size_t)(wc      + l31) * F + lhalf * 8;
    const u16* pb1 = Bg + (size_t)(wc + 32 + l31) * F + lhalf * 8;

    f32x16 acc[2][2];
    #pragma unroll
    for (int i = 0; i < 2; ++i)
        #pragma unroll
        for (int j = 0; j < 2; ++j)
            #pragma unroll
            for (int r = 0; r < 16; ++r) acc[i][j][r] = 0.0f;

    // 16 k16-steps; offsets ks*16 halves = ks*32 B -> immediate offsets.
    #pragma unroll
    for (int ks = 0; ks < 16; ++ks) {
        const int off = ks * 16;
        const f16x8 a0 = *(const f16x8*)(pa0 + off);
        const f16x8 a1 = *(const f16x8*)(pa1 + off);
        const f16x8 b0 = *(const f16x8*)(pb0 + off);
        const f16x8 b1 = *(const f16x8*)(pb1 + off);
        acc[0][0] = __builtin_amdgcn_mfma_f32_32x32x16_f16(a0, b0, acc[0][0], 0, 0, 0);
        acc[0][1] = __builtin_amdgcn_mfma_f32_32x32x16_f16(a0, b1, acc[0][1], 0, 0, 0);
        acc[1][0] = __builtin_amdgcn_mfma_f32_32x32x16_f16(a1, b0, acc[1][0], 0, 0, 0);
        acc[1][1] = __builtin_amdgcn_mfma_f32_32x32x16_f16(a1, b1, acc[1][1], 0, 0, 0);
    }

    // ---- block-wide min/max over all 16384 scores (position-agnostic) ----
    float vmin = acc[0][0][0];
    float vmax = acc[0][0][0];
    #pragma unroll
    for (int i = 0; i < 2; ++i)
        #pragma unroll
        for (int j = 0; j < 2; ++j)
            #pragma unroll
            for (int r = 0; r < 16; ++r) {
                vmin = fminf(vmin, acc[i][j][r]);
                vmax = fmaxf(vmax, acc[i][j][r]);
            }
    #pragma unroll
    for (int off = 32; off > 0; off >>= 1) {
        vmin = fminf(vmin, __shfl_down(vmin, off, 64));
        vmax = fmaxf(vmax, __shfl_down(vmax, off, 64));
    }
    if (lane == 0) { sred[w] = vmin; sred[4 + w] = vmax; }
    __syncthreads();
    const float mn = fminf(fminf(sred[0], sred[1]), fminf(sred[2], sred[3]));
    const float mx = fmaxf(fmaxf(sred[4], sred[5]), fmaxf(sred[6], sred[7]));
    const float denom = (mx > mn) ? (mx - mn) : 1.0f;
    const float scale = 8.0f / denom;
    const float bias  = -mn * scale;

    // ---- per-thread packed histogram (8 bins, 8-bit fields, max 64/thread) ----
    // (x-mn)*scale >= 0 always, so trunc == floor and no low clamp needed.
    unsigned w0 = 0, w1 = 0;
    #pragma unroll
    for (int i = 0; i < 2; ++i)
        #pragma unroll
        for (int j = 0; j < 2; ++j)
            #pragma unroll
            for (int r = 0; r < 16; ++r) {
                const float t = fmaf(acc[i][j][r], scale, bias);
                int k = (int)t;
                k = k > 7 ? 7 : k;
                const unsigned inc = 1u << ((k & 3) * 8);
                if (k < 4) w0 += inc; else w1 += inc;
            }

    unsigned e0 = (w0 & 0xFFu)         | (((w0 >> 8)  & 0xFFu) << 16);
    unsigned e1 = ((w0 >> 16) & 0xFFu) | (((w0 >> 24) & 0xFFu) << 16);
    unsigned e2 = (w1 & 0xFFu)         | (((w1 >> 8)  & 0xFFu) << 16);
    unsigned e3 = ((w1 >> 16) & 0xFFu) | (((w1 >> 24) & 0xFFu) << 16);
    #pragma unroll
    for (int off = 32; off > 0; off >>= 1) {
        e0 += __shfl_down(e0, off, 64);
        e1 += __shfl_down(e1, off, 64);
        e2 += __shfl_down(e2, off, 64);
        e3 += __shfl_down(e3, off, 64);
    }
    if (lane == 0) {
        atomicAdd(&hist[0], (int)(e0 & 0xFFFFu)); atomicAdd(&hist[1], (int)(e0 >> 16));
        atomicAdd(&hist[2], (int)(e1 & 0xFFFFu)); atomicAdd(&hist[3], (int)(e1 >> 16));
        atomicAdd(&hist[4], (int)(e2 & 0xFFFFu)); atomicAdd(&hist[5], (int)(e2 >> 16));
        atomicAdd(&hist[6], (int)(e3 & 0xFFFFu)); atomicAdd(&hist[7], (int)(e3 >> 16));
    }
    __syncthreads();

    // ---- normalize and write both symmetric rows ----
    if (tid < 8) {
        float ss = 0.0f;
        #pragma unroll
        for (int i = 0; i < 8; ++i) {
            const float c = (float)hist[i];
            ss += c * c;
        }
        const float nrm = fmaxf(sqrtf(ss), 1e-12f);
        const float v = (float)hist[tid] / nrm;
        out[((size_t)a * BS + b) * 16 + mat * 8 + tid] = v;
        if (a != b)
            out[((size_t)b * BS + a) * 16 + mat * 8 + tid] = v;
    }
}

extern "C" void kernel_launch(void* const* d_in, const int* in_sizes, int n_in,
                              void* d_out, int out_size, void* d_ws, size_t ws_size,
                              hipStream_t stream) {
    const float* m1 = (const float*)d_in[0];
    const float* m2 = (const float*)d_in[1];
    float* out = (float*)d_out;

    // Workspace: transposed fp16 array, 2*64*128*256 u16 = 8.39 MB.
    u16* hT = (u16*)d_ws;

    convert_f16_kernel<<<dim3(128, 4), 256, 0, stream>>>(m1, m2, hT);
    gram_hist_mfma<<<dim3(NPAIRS, 2), 256, 0, stream>>>(hT, out);
}

// Round 5
// 162.012 us; speedup vs baseline: 1.1864x; 1.1864x over previous
//
#include <hip/hip_runtime.h>
#include <math.h>

// Problem constants (from reference setup_inputs)
#define BS 64      // batch
#define F  256     // features (K of the Gram matmul)
#define M  128     // columns  (M=N of the Gram matmul)
#define MF (M * F)
#define NTILE 32     // 32 super-tiles of 2 matrices each (256 rows)
#define NTPAIRS 528  // 32*33/2 super-tile pairs i<=j; each covers 4 (a,b) pairs

typedef unsigned short u16;
typedef _Float16 f16x8 __attribute__((ext_vector_type(8)));
typedef float    f32x16 __attribute__((ext_vector_type(16)));

// ---------------------------------------------------------------------------
// Pre-pass: fp32 -> fp16 (RNE) + transpose [f][m] -> [m][f] via LDS.
// (verified rounds 2-4; absmax 0.0039 with single-pass fp16.)
// ---------------------------------------------------------------------------
__global__ __launch_bounds__(256) void convert_f16_kernel(
    const float* __restrict__ m1, const float* __restrict__ m2,
    u16* __restrict__ hT)
{
    __shared__ float tile[64 * M];   // 32 KB
    const int mat = blockIdx.x >> 6;
    const int b   = blockIdx.x & 63;
    const int f0  = blockIdx.y * 64;
    const float* src = (mat == 0 ? m1 : m2) + (size_t)b * MF + (size_t)f0 * M;
    const size_t obase = (size_t)(mat * BS + b) * MF;
    const int tid = threadIdx.x;

    const float4* g = (const float4*)src;
    float4* s = (float4*)tile;
    #pragma unroll
    for (int i = 0; i < 8; ++i)
        s[tid + i * 256] = g[tid + i * 256];
    __syncthreads();

    const int m  = tid >> 1;
    const int fb = (tid & 1) * 8;
    #pragma unroll
    for (int pass = 0; pass < 4; ++pass) {
        const int fs = fb + pass * 16;
        u16 hh[8] __attribute__((aligned(16)));
        #pragma unroll
        for (int j = 0; j < 8; ++j) {
            const float x = tile[(fs + j) * M + m];
            const _Float16 h = (_Float16)x;
            hh[j] = __builtin_bit_cast(u16, h);
        }
        *(uint4*)&hT[obase + (size_t)m * F + f0 + fs] = *(const uint4*)hh;
    }
}

__device__ __forceinline__ void async16(const u16* g, u16* l) {
    __builtin_amdgcn_global_load_lds(
        (const __attribute__((address_space(1))) unsigned int*)g,
        (__attribute__((address_space(3))) unsigned int*)l, 16, 0, 0);
}

// ---------------------------------------------------------------------------
// One block per (super-tile pair (i,j), mat). Block C-tile = 256x256 covering
// the 4 pairs (2i+da, 2j+db). 4 waves; wave w = (da=w>>1, db=w&1) owns the
// FULL 128x128 score region of its pair -> per-wave epilogue, no atomics,
// no post-loop barriers. acc = 16 x f32x16 (256 AGPRs, 1 wave/SIMD).
// LDS: double-buffered [buf][side A/B][kb 0..3][row 0..255][8 f16] = 2x32 KB.
// Staging via global_load_lds (lane-contiguous dest); ds_read_b128 fragments
// (0 bank conflicts, verified rounds 2-3). Loads for chunk k+1 issue BEFORE
// compute on chunk k -> the vmcnt(0) barrier drain is covered by compute.
// ---------------------------------------------------------------------------
__global__ __launch_bounds__(256, 1) void gram_hist_mfma(
    const u16* __restrict__ hT, float* __restrict__ out)
{
    __shared__ u16 lds[32768];   // 64 KB = 2 buffers x (A 16KB + B 16KB)

    const int tid  = threadIdx.x;
    const int lane = tid & 63;
    const int w    = tid >> 6;

    // Decode super-tile pair blockIdx.x -> (i, j), i <= j (uniform loop).
    int p = blockIdx.x, i = 0;
    { int cnt = NTILE; while (p >= cnt) { p -= cnt; ++i; --cnt; } }
    const int j = i + p;
    const int mat = blockIdx.y;

    // Row sources: A-side = matrices {2i, 2i+1}, B-side = {2j, 2j+1}.
    const u16* srcs[4] = {
        hT + (size_t)(mat * BS + 2 * i)     * MF,
        hT + (size_t)(mat * BS + 2 * i + 1) * MF,
        hT + (size_t)(mat * BS + 2 * j)     * MF,
        hT + (size_t)(mat * BS + 2 * j + 1) * MF,
    };

    const int mrow = tid & 127;   // row within matrix for staging
    const int msel = tid >> 7;    // which of the 2 matrices per side

    // Stage one 32-k chunk (both sides) into buffer at half-offset `bufo`.
    // gi = t*256+tid -> dst halves = bufo + gi*8 (lane-contiguous, 16B/lane).
    // Layout: side = t>>2, kb = t&3, r = tid  ->  [side][kb][r][8].
    auto stage = [&](int bufo, int k0) {
        #pragma unroll
        for (int t = 0; t < 8; ++t) {
            const u16* s = srcs[(t >> 2) * 2 + msel] + (size_t)mrow * F + k0 + (t & 3) * 8;
            async16(s, &lds[bufo + (t * 256 + tid) * 8]);
        }
    };

    const int br = (w >> 1) * 128;   // wave's A row band within 256
    const int bc = (w & 1)  * 128;   // wave's B row band within 256
    const int l31   = lane & 31;
    const int lhalf = lane >> 5;

    f32x16 acc[4][4];
    #pragma unroll
    for (int ti = 0; ti < 4; ++ti)
        #pragma unroll
        for (int tj = 0; tj < 4; ++tj)
            #pragma unroll
            for (int r = 0; r < 16; ++r) acc[ti][tj][r] = 0.0f;

    stage(0, 0);
    __syncthreads();

    for (int it = 0; it < 8; ++it) {
        const int cur = (it & 1) * 16384;
        if (it < 7) stage(cur ^ 16384, (it + 1) * 32);   // prefetch next chunk

        #pragma unroll
        for (int kk = 0; kk < 2; ++kk) {
            const int kb = kk * 2 + lhalf;
            f16x8 af[4], bf[4];
            #pragma unroll
            for (int t = 0; t < 4; ++t) {
                af[t] = *(const f16x8*)&lds[cur +        (kb * 256 + br + t * 32 + l31) * 8];
                bf[t] = *(const f16x8*)&lds[cur + 8192 + (kb * 256 + bc + t * 32 + l31) * 8];
            }
            #pragma unroll
            for (int ti = 0; ti < 4; ++ti)
                #pragma unroll
                for (int tj = 0; tj < 4; ++tj)
                    acc[ti][tj] = __builtin_amdgcn_mfma_f32_32x32x16_f16(af[ti], bf[tj], acc[ti][tj], 0, 0, 0);
        }
        __syncthreads();   // waves done with cur; prefetch loads drained
    }

    // ---- per-wave epilogue: this wave's pair is (A, B) ----
    const int A = 2 * i + (w >> 1);
    const int B = 2 * j + (w & 1);
    if (A > B) return;   // transpose-duplicate region (diagonal blocks only)

    // wave-wide min/max over the pair's 16384 scores (butterfly -> all lanes)
    float vmin = acc[0][0][0];
    float vmax = vmin;
    #pragma unroll
    for (int ti = 0; ti < 4; ++ti)
        #pragma unroll
        for (int tj = 0; tj < 4; ++tj)
            #pragma unroll
            for (int r = 0; r < 16; ++r) {
                vmin = fminf(vmin, acc[ti][tj][r]);
                vmax = fmaxf(vmax, acc[ti][tj][r]);
            }
    #pragma unroll
    for (int off = 1; off < 64; off <<= 1) {
        vmin = fminf(vmin, __shfl_xor(vmin, off, 64));
        vmax = fmaxf(vmax, __shfl_xor(vmax, off, 64));
    }
    const float denom = (vmax > vmin) ? (vmax - vmin) : 1.0f;
    const float scale = 8.0f / denom;
    const float bias  = -vmin * scale;

    // histogram: two half-passes of 128 values (8-bit packed, <=128/bin),
    // expanded into 16-bit fields (wave totals <=16384).
    unsigned e0 = 0, e1 = 0, e2 = 0, e3 = 0;
    #pragma unroll
    for (int half = 0; half < 2; ++half) {
        unsigned w0 = 0, w1 = 0;
        #pragma unroll
        for (int ti = half * 2; ti < half * 2 + 2; ++ti)
            #pragma unroll
            for (int tj = 0; tj < 4; ++tj)
                #pragma unroll
                for (int r = 0; r < 16; ++r) {
                    const float t = fmaf(acc[ti][tj][r], scale, bias);
                    int k = (int)t;            // t >= 0, trunc == floor
                    k = k > 7 ? 7 : k;
                    const unsigned inc = 1u << ((k & 3) * 8);
                    if (k < 4) w0 += inc; else w1 += inc;
                }
        e0 += (w0 & 0xFFu)         | (((w0 >> 8)  & 0xFFu) << 16);
        e1 += ((w0 >> 16) & 0xFFu) | (((w0 >> 24) & 0xFFu) << 16);
        e2 += (w1 & 0xFFu)         | (((w1 >> 8)  & 0xFFu) << 16);
        e3 += ((w1 >> 16) & 0xFFu) | (((w1 >> 24) & 0xFFu) << 16);
    }
    #pragma unroll
    for (int off = 32; off > 0; off >>= 1) {
        e0 += __shfl_down(e0, off, 64);
        e1 += __shfl_down(e1, off, 64);
        e2 += __shfl_down(e2, off, 64);
        e3 += __shfl_down(e3, off, 64);
    }

    if (lane == 0) {
        float bins[8] = {
            (float)(e0 & 0xFFFFu), (float)(e0 >> 16),
            (float)(e1 & 0xFFFFu), (float)(e1 >> 16),
            (float)(e2 & 0xFFFFu), (float)(e2 >> 16),
            (float)(e3 & 0xFFFFu), (float)(e3 >> 16),
        };
        float ss = 0.0f;
        #pragma unroll
        for (int k = 0; k < 8; ++k) ss += bins[k] * bins[k];
        const float nrm = fmaxf(sqrtf(ss), 1e-12f);
        const size_t o1 = ((size_t)A * BS + B) * 16 + mat * 8;
        const size_t o2 = ((size_t)B * BS + A) * 16 + mat * 8;
        #pragma unroll
        for (int k = 0; k < 8; ++k) {
            const float v = bins[k] / nrm;
            out[o1 + k] = v;
            if (A != B) out[o2 + k] = v;
        }
    }
}

extern "C" void kernel_launch(void* const* d_in, const int* in_sizes, int n_in,
                              void* d_out, int out_size, void* d_ws, size_t ws_size,
                              hipStream_t stream) {
    const float* m1 = (const float*)d_in[0];
    const float* m2 = (const float*)d_in[1];
    float* out = (float*)d_out;

    // Workspace: transposed fp16 array, 2*64*128*256 u16 = 8.39 MB.
    u16* hT = (u16*)d_ws;

    convert_f16_kernel<<<dim3(128, 4), 256, 0, stream>>>(m1, m2, hT);
    gram_hist_mfma<<<dim3(NTPAIRS, 2), 256, 0, stream>>>(hT, out);
}

// Round 6
// 120.698 us; speedup vs baseline: 1.5925x; 1.3423x over previous
//
#include <hip/hip_runtime.h>
#include <math.h>

// Problem constants (from reference setup_inputs)
#define BS 64      // batch
#define F  256     // features (K of the Gram matmul)
#define M  128     // columns  (M=N of the Gram matmul)
#define MF (M * F) // u16 elements per matrix in hT
#define NBP 1056   // blocks per mat: sum_a ceil((64-a)/2)

typedef unsigned short u16;
typedef _Float16 f16x8 __attribute__((ext_vector_type(8)));
typedef float    f32x16 __attribute__((ext_vector_type(16)));

// ---------------------------------------------------------------------------
// Pre-pass: fp32 [f][m] -> fp16 GRANULE-MAJOR hT[b][f8][m][8].
// A 32-k chunk of one matrix is 4 f8-rows = 4 KB x ... = one contiguous 8 KB
// block, so GEMM staging is a straight contiguous copy (16 cache lines per
// global_load_lds instead of 64 -- the round-3/5 staging was a 512B-stride
// gather, the dominant cost per the round-4/5 TA analysis).
// Grid: (128 = mat*64+b, 4 = f-chunk of 64).
// ---------------------------------------------------------------------------
__global__ __launch_bounds__(256) void convert_f16_kernel(
    const float* __restrict__ m1, const float* __restrict__ m2,
    u16* __restrict__ hT)
{
    __shared__ float tile[64 * M];   // 32 KB
    const int mat = blockIdx.x >> 6;
    const int b   = blockIdx.x & 63;
    const int f0  = blockIdx.y * 64;
    const float* src = (mat == 0 ? m1 : m2) + (size_t)b * MF + (size_t)f0 * M;
    const int tid = threadIdx.x;

    const float4* g = (const float4*)src;
    float4* s = (float4*)tile;
    #pragma unroll
    for (int i = 0; i < 8; ++i)
        s[tid + i * 256] = g[tid + i * 256];
    __syncthreads();

    // granule idx (local): f8l = idx>>7 (0..7), m = idx&127. Writes are
    // lane-contiguous 16B -> fully coalesced.
    const size_t obase = ((size_t)(mat * BS + b) * 32 + (f0 >> 3)) * 1024;
    #pragma unroll
    for (int it = 0; it < 4; ++it) {
        const int idx = it * 256 + tid;
        const int f8l = idx >> 7;
        const int m   = idx & 127;
        u16 hh[8] __attribute__((aligned(16)));
        #pragma unroll
        for (int j = 0; j < 8; ++j) {
            const float x = tile[(f8l * 8 + j) * M + m];  // 2 lanes/bank: free
            const _Float16 h = (_Float16)x;               // RNE
            hh[j] = __builtin_bit_cast(u16, h);
        }
        *(uint4*)&hT[obase + (size_t)idx * 8] = *(const uint4*)hh;
    }
}

__device__ __forceinline__ void async16(const u16* g, u16* l) {
    __builtin_amdgcn_global_load_lds(
        (const __attribute__((address_space(1))) unsigned int*)g,
        (__attribute__((address_space(3))) unsigned int*)l, 16, 0, 0);
}

// ---------------------------------------------------------------------------
// One block per (a, b-pair): computes pairs (a,b1) and (a,b2=b1+1), sharing
// the A-tile. 4 waves; wave w = (pair p=w>>1, col-half c=w&1) computes a
// 128x64 region: acc = 8 x f32x16 = 128 AGPR -> 2 waves/SIMD resident
// (round 5's 256-AGPR tile collapsed to 1 wave/SIMD; that was the failure).
// LDS: double-buffered [buf][{A,B1,B2} 8KB][kb][m][8] = 48 KB; global layout
// == LDS layout, so staging is contiguous; ds_read_b128 fragments unchanged
// from rounds 2-5 (0 conflicts). Prefetch chunk k+1 before compute on k.
// ---------------------------------------------------------------------------
__global__ __launch_bounds__(256, 2) void gram_hist_mfma(
    const u16* __restrict__ hT, float* __restrict__ out)
{
    __shared__ u16 lds[2 * 12288];   // 48 KB
    __shared__ float smin[4], smax[4];
    __shared__ int hist[2][8];

    const int tid  = threadIdx.x;
    const int lane = tid & 63;
    const int w    = tid >> 6;

    if (tid < 16) hist[tid >> 3][tid & 7] = 0;

    // Decode blockIdx.x -> (a, p) with per-a count ceil((64-a)/2).
    int p = blockIdx.x, a = 0;
    { int cnt = 32; while (p >= cnt) { p -= cnt; ++a; cnt = (64 - a + 1) >> 1; } }
    const int b1 = a + 2 * p;
    int b2 = b1 + 1;
    const bool b2valid = (b2 <= 63);
    if (!b2valid) b2 = b1;          // duplicate work, writes suppressed
    const int mat = blockIdx.y;

    const u16* Asrc  = hT + (size_t)(mat * BS + a)  * MF;
    const u16* B1src = hT + (size_t)(mat * BS + b1) * MF;
    const u16* B2src = hT + (size_t)(mat * BS + b2) * MF;

    // Stage one 32-k chunk (A,B1,B2 = 3 x 8KB contiguous) into buffer bufo.
    auto stage = [&](int bufo, int k0) {
        const int koff = k0 * 128;   // u16 offset of the chunk within a matrix
        #pragma unroll
        for (int g = 0; g < 6; ++g) {
            const int idx = (g & 1) * 256 + tid;   // 0..511, lane-contiguous
            const u16* s = (g < 2 ? Asrc : (g < 4 ? B1src : B2src)) + koff + idx * 8;
            async16(s, &lds[bufo + (g >> 1) * 4096 + idx * 8]);
        }
    };

    const int pp = w >> 1;     // which pair (0: b1, 1: b2)
    const int c  = w & 1;      // which 64-col half
    const int l31   = lane & 31;
    const int lhalf = lane >> 5;

    f32x16 acc[4][2];
    #pragma unroll
    for (int ti = 0; ti < 4; ++ti)
        #pragma unroll
        for (int u = 0; u < 2; ++u)
            #pragma unroll
            for (int r = 0; r < 16; ++r) acc[ti][u][r] = 0.0f;

    stage(0, 0);
    __syncthreads();

    for (int it = 0; it < 8; ++it) {
        const int cur = (it & 1) * 12288;
        if (it < 7) stage(cur ^ 12288, (it + 1) * 32);   // prefetch next

        #pragma unroll
        for (int kk = 0; kk < 2; ++kk) {
            const int kb = kk * 2 + lhalf;
            f16x8 af[4], bf[2];
            #pragma unroll
            for (int t = 0; t < 4; ++t)
                af[t] = *(const f16x8*)&lds[cur + (kb * 128 + t * 32 + l31) * 8];
            #pragma unroll
            for (int t = 0; t < 2; ++t)
                bf[t] = *(const f16x8*)&lds[cur + (1 + pp) * 4096 + (kb * 128 + c * 64 + t * 32 + l31) * 8];
            #pragma unroll
            for (int ti = 0; ti < 4; ++ti)
                #pragma unroll
                for (int u = 0; u < 2; ++u)
                    acc[ti][u] = __builtin_amdgcn_mfma_f32_32x32x16_f16(af[ti], bf[u], acc[ti][u], 0, 0, 0);
        }
        __syncthreads();   // everyone done with cur; prefetch drained (covered by compute)
    }

    // ---- epilogue: pair pp is owned by waves (pp,c=0) and (pp,c=1) ----
    // wave min/max over this wave's 128 values -> butterfly to all lanes
    float vmin = acc[0][0][0], vmax = vmin;
    #pragma unroll
    for (int ti = 0; ti < 4; ++ti)
        #pragma unroll
        for (int u = 0; u < 2; ++u)
            #pragma unroll
            for (int r = 0; r < 16; ++r) {
                vmin = fminf(vmin, acc[ti][u][r]);
                vmax = fmaxf(vmax, acc[ti][u][r]);
            }
    #pragma unroll
    for (int off = 1; off < 64; off <<= 1) {
        vmin = fminf(vmin, __shfl_xor(vmin, off, 64));
        vmax = fmaxf(vmax, __shfl_xor(vmax, off, 64));
    }
    if (lane == 0) { smin[w] = vmin; smax[w] = vmax; }
    __syncthreads();
    const float pmn = fminf(smin[pp * 2], smin[pp * 2 + 1]);
    const float pmx = fmaxf(smax[pp * 2], smax[pp * 2 + 1]);
    const float denom = (pmx > pmn) ? (pmx - pmn) : 1.0f;
    const float scale = 8.0f / denom;
    const float bias  = -pmn * scale;

    // per-thread packed histogram: 128 values -> 8-bit fields (<=128/bin ok)
    unsigned w0 = 0, w1 = 0;
    #pragma unroll
    for (int ti = 0; ti < 4; ++ti)
        #pragma unroll
        for (int u = 0; u < 2; ++u)
            #pragma unroll
            for (int r = 0; r < 16; ++r) {
                const float t = fmaf(acc[ti][u][r], scale, bias);
                int k = (int)t;          // t >= -eps; trunc == floor; (int)(-0.0)=0
                k = k > 7 ? 7 : k;
                const unsigned inc = 1u << ((k & 3) * 8);
                if (k < 4) w0 += inc; else w1 += inc;
            }
    unsigned e0 = (w0 & 0xFFu)         | (((w0 >> 8)  & 0xFFu) << 16);
    unsigned e1 = ((w0 >> 16) & 0xFFu) | (((w0 >> 24) & 0xFFu) << 16);
    unsigned e2 = (w1 & 0xFFu)         | (((w1 >> 8)  & 0xFFu) << 16);
    unsigned e3 = ((w1 >> 16) & 0xFFu) | (((w1 >> 24) & 0xFFu) << 16);
    #pragma unroll
    for (int off = 32; off > 0; off >>= 1) {
        e0 += __shfl_down(e0, off, 64);
        e1 += __shfl_down(e1, off, 64);
        e2 += __shfl_down(e2, off, 64);
        e3 += __shfl_down(e3, off, 64);
    }
    if (lane == 0) {
        atomicAdd(&hist[pp][0], (int)(e0 & 0xFFFFu)); atomicAdd(&hist[pp][1], (int)(e0 >> 16));
        atomicAdd(&hist[pp][2], (int)(e1 & 0xFFFFu)); atomicAdd(&hist[pp][3], (int)(e1 >> 16));
        atomicAdd(&hist[pp][4], (int)(e2 & 0xFFFFu)); atomicAdd(&hist[pp][5], (int)(e2 >> 16));
        atomicAdd(&hist[pp][6], (int)(e3 & 0xFFFFu)); atomicAdd(&hist[pp][7], (int)(e3 >> 16));
    }
    __syncthreads();

    // one wave per pair normalizes and writes both symmetric rows
    const int B = (pp == 0) ? b1 : b2;
    const bool valid = (pp == 0) || b2valid;
    if (valid && c == 0 && lane < 8) {
        float ss = 0.0f;
        #pragma unroll
        for (int k = 0; k < 8; ++k) {
            const float cc = (float)hist[pp][k];
            ss += cc * cc;
        }
        const float nrm = fmaxf(sqrtf(ss), 1e-12f);
        const float v = (float)hist[pp][lane] / nrm;
        out[((size_t)a * BS + B) * 16 + mat * 8 + lane] = v;
        if (a != B)
            out[((size_t)B * BS + a) * 16 + mat * 8 + lane] = v;
    }
}

extern "C" void kernel_launch(void* const* d_in, const int* in_sizes, int n_in,
                              void* d_out, int out_size, void* d_ws, size_t ws_size,
                              hipStream_t stream) {
    const float* m1 = (const float*)d_in[0];
    const float* m2 = (const float*)d_in[1];
    float* out = (float*)d_out;

    // Workspace: granule-major fp16 array, 2*64*128*256 u16 = 8.39 MB.
    u16* hT = (u16*)d_ws;

    convert_f16_kernel<<<dim3(128, 4), 256, 0, stream>>>(m1, m2, hT);
    gram_hist_mfma<<<dim3(NBP, 2), 256, 0, stream>>>(hT, out);
}

// Round 7
// 120.679 us; speedup vs baseline: 1.5927x; 1.0002x over previous
//
#include <hip/hip_runtime.h>
#include <math.h>

// Problem constants (from reference setup_inputs)
#define BS 64      // batch
#define F  256     // features (K of the Gram matmul)
#define M  128     // columns  (M=N of the Gram matmul)
#define MF (M * F) // u16 elements per matrix in hT
#define NBP 1056   // blocks per mat: sum_a ceil((64-a)/2)

typedef unsigned short u16;
typedef _Float16 f16x8 __attribute__((ext_vector_type(8)));
typedef float    f32x16 __attribute__((ext_vector_type(16)));

// ---------------------------------------------------------------------------
// Pre-pass: fp32 [f][m] -> fp16 GRANULE-MAJOR hT[b][f8][m][8]. (round 6:
// coalesced staging was worth 107->58 us; layout verified.)
// ---------------------------------------------------------------------------
__global__ __launch_bounds__(256) void convert_f16_kernel(
    const float* __restrict__ m1, const float* __restrict__ m2,
    u16* __restrict__ hT)
{
    __shared__ float tile[64 * M];   // 32 KB
    const int mat = blockIdx.x >> 6;
    const int b   = blockIdx.x & 63;
    const int f0  = blockIdx.y * 64;
    const float* src = (mat == 0 ? m1 : m2) + (size_t)b * MF + (size_t)f0 * M;
    const int tid = threadIdx.x;

    const float4* g = (const float4*)src;
    float4* s = (float4*)tile;
    #pragma unroll
    for (int i = 0; i < 8; ++i)
        s[tid + i * 256] = g[tid + i * 256];
    __syncthreads();

    const size_t obase = ((size_t)(mat * BS + b) * 32 + (f0 >> 3)) * 1024;
    #pragma unroll
    for (int it = 0; it < 4; ++it) {
        const int idx = it * 256 + tid;
        const int f8l = idx >> 7;
        const int m   = idx & 127;
        u16 hh[8] __attribute__((aligned(16)));
        #pragma unroll
        for (int j = 0; j < 8; ++j) {
            const float x = tile[(f8l * 8 + j) * M + m];  // 2 lanes/bank: free
            const _Float16 h = (_Float16)x;               // RNE
            hh[j] = __builtin_bit_cast(u16, h);
        }
        *(uint4*)&hT[obase + (size_t)idx * 8] = *(const uint4*)hh;
    }
}

__device__ __forceinline__ void async16(const u16* g, u16* l) {
    __builtin_amdgcn_global_load_lds(
        (const __attribute__((address_space(1))) unsigned int*)g,
        (__attribute__((address_space(3))) unsigned int*)l, 16, 0, 0);
}

// ---------------------------------------------------------------------------
// One block = 512 threads = 8 waves, covering 2 pairs (a,b1),(a,b2=b1+1)
// sharing the A-tile. Wave w: pp=w>>2 (pair), rr=(w>>1)&1, cc=w&1 -> wave
// computes the 64x64 C-quadrant (rows rr*64.., cols cc*64..) of pair pp.
// acc = 4 x f32x16 = 64 AGPR -> <=128 regs/wave -> 4 waves/SIMD (16/CU):
// round 6 was register-capped at 2 waves/SIMD (acc=128); stalls, not pipe
// throughput, dominated. LDS: double-buffered [buf][{A,B1,B2} 8KB] = 48 KB,
// granule-major == global layout (coalesced DMA, 0 bank conflicts).
// ---------------------------------------------------------------------------
__global__ __launch_bounds__(512, 4) void gram_hist_mfma(
    const u16* __restrict__ hT, float* __restrict__ out)
{
    __shared__ u16 lds[2 * 12288];   // 48 KB
    __shared__ float smin[8], smax[8];
    __shared__ int hist[2][8];

    const int tid  = threadIdx.x;
    const int lane = tid & 63;
    const int w    = tid >> 6;

    if (tid < 16) hist[tid >> 3][tid & 7] = 0;

    // Decode blockIdx.x -> (a, p) with per-a count ceil((64-a)/2).
    int p = blockIdx.x, a = 0;
    { int cnt = 32; while (p >= cnt) { p -= cnt; ++a; cnt = (64 - a + 1) >> 1; } }
    const int b1 = a + 2 * p;
    int b2 = b1 + 1;
    const bool b2valid = (b2 <= 63);
    if (!b2valid) b2 = b1;          // duplicate work, writes suppressed
    const int mat = blockIdx.y;

    const u16* srcs[3] = {
        hT + (size_t)(mat * BS + a)  * MF,
        hT + (size_t)(mat * BS + b1) * MF,
        hT + (size_t)(mat * BS + b2) * MF,
    };

    // Stage one 32-k chunk (A,B1,B2 = 3 x 8KB contiguous): 3 async16/thread.
    auto stage = [&](int bufo, int koff) {
        #pragma unroll
        for (int g = 0; g < 3; ++g)
            async16(srcs[g] + koff + tid * 8, &lds[bufo + g * 4096 + tid * 8]);
    };

    const int pp = w >> 2;          // pair (0: b1, 1: b2)
    const int rr = (w >> 1) & 1;    // row half
    const int cc = w & 1;           // col half
    const int l31   = lane & 31;
    const int lhalf = lane >> 5;

    f32x16 acc[2][2];
    #pragma unroll
    for (int ti = 0; ti < 2; ++ti)
        #pragma unroll
        for (int tj = 0; tj < 2; ++tj)
            #pragma unroll
            for (int r = 0; r < 16; ++r) acc[ti][tj][r] = 0.0f;

    stage(0, 0);
    __syncthreads();

    for (int it = 0; it < 8; ++it) {
        const int cur = (it & 1) * 12288;
        if (it < 7) stage(cur ^ 12288, (it + 1) * 4096);   // prefetch next chunk

        #pragma unroll
        for (int kk = 0; kk < 2; ++kk) {
            const int kb = kk * 2 + lhalf;
            f16x8 af[2], bf[2];
            #pragma unroll
            for (int t = 0; t < 2; ++t) {
                af[t] = *(const f16x8*)&lds[cur + (kb * 128 + rr * 64 + t * 32 + l31) * 8];
                bf[t] = *(const f16x8*)&lds[cur + (1 + pp) * 4096 + (kb * 128 + cc * 64 + t * 32 + l31) * 8];
            }
            #pragma unroll
            for (int ti = 0; ti < 2; ++ti)
                #pragma unroll
                for (int tj = 0; tj < 2; ++tj)
                    acc[ti][tj] = __builtin_amdgcn_mfma_f32_32x32x16_f16(af[ti], bf[tj], acc[ti][tj], 0, 0, 0);
        }
        __syncthreads();   // waves done with cur; prefetch drained under compute
    }

    // ---- epilogue: pair pp owned by 4 waves (rr,cc) ----
    float vmin = acc[0][0][0], vmax = vmin;
    #pragma unroll
    for (int ti = 0; ti < 2; ++ti)
        #pragma unroll
        for (int tj = 0; tj < 2; ++tj)
            #pragma unroll
            for (int r = 0; r < 16; ++r) {
                vmin = fminf(vmin, acc[ti][tj][r]);
                vmax = fmaxf(vmax, acc[ti][tj][r]);
            }
    #pragma unroll
    for (int off = 1; off < 64; off <<= 1) {
        vmin = fminf(vmin, __shfl_xor(vmin, off, 64));
        vmax = fmaxf(vmax, __shfl_xor(vmax, off, 64));
    }
    if (lane == 0) { smin[w] = vmin; smax[w] = vmax; }
    __syncthreads();
    const int hb = pp * 4;
    const float pmn = fminf(fminf(smin[hb], smin[hb + 1]), fminf(smin[hb + 2], smin[hb + 3]));
    const float pmx = fmaxf(fmaxf(smax[hb], smax[hb + 1]), fmaxf(smax[hb + 2], smax[hb + 3]));
    const float denom = (pmx > pmn) ? (pmx - pmn) : 1.0f;
    const float scale = 8.0f / denom;
    const float bias  = -pmn * scale;

    // per-thread packed histogram: 64 values -> 8-bit fields (<=64/bin)
    unsigned w0 = 0, w1 = 0;
    #pragma unroll
    for (int ti = 0; ti < 2; ++ti)
        #pragma unroll
        for (int tj = 0; tj < 2; ++tj)
            #pragma unroll
            for (int r = 0; r < 16; ++r) {
                const float t = fmaf(acc[ti][tj][r], scale, bias);
                int k = (int)t;          // t >= -eps; trunc == floor
                k = k > 7 ? 7 : k;
                const unsigned inc = 1u << ((k & 3) * 8);
                if (k < 4) w0 += inc; else w1 += inc;
            }
    unsigned e0 = (w0 & 0xFFu)         | (((w0 >> 8)  & 0xFFu) << 16);
    unsigned e1 = ((w0 >> 16) & 0xFFu) | (((w0 >> 24) & 0xFFu) << 16);
    unsigned e2 = (w1 & 0xFFu)         | (((w1 >> 8)  & 0xFFu) << 16);
    unsigned e3 = ((w1 >> 16) & 0xFFu) | (((w1 >> 24) & 0xFFu) << 16);
    #pragma unroll
    for (int off = 32; off > 0; off >>= 1) {
        e0 += __shfl_down(e0, off, 64);
        e1 += __shfl_down(e1, off, 64);
        e2 += __shfl_down(e2, off, 64);
        e3 += __shfl_down(e3, off, 64);
    }
    if (lane == 0) {
        atomicAdd(&hist[pp][0], (int)(e0 & 0xFFFFu)); atomicAdd(&hist[pp][1], (int)(e0 >> 16));
        atomicAdd(&hist[pp][2], (int)(e1 & 0xFFFFu)); atomicAdd(&hist[pp][3], (int)(e1 >> 16));
        atomicAdd(&hist[pp][4], (int)(e2 & 0xFFFFu)); atomicAdd(&hist[pp][5], (int)(e2 >> 16));
        atomicAdd(&hist[pp][6], (int)(e3 & 0xFFFFu)); atomicAdd(&hist[pp][7], (int)(e3 >> 16));
    }
    __syncthreads();

    // one wave per pair normalizes and writes both symmetric rows
    const int B = (pp == 0) ? b1 : b2;
    const bool valid = (pp == 0) || b2valid;
    if (valid && rr == 0 && cc == 0 && lane < 8) {
        float ss = 0.0f;
        #pragma unroll
        for (int k = 0; k < 8; ++k) {
            const float c = (float)hist[pp][k];
            ss += c * c;
        }
        const float nrm = fmaxf(sqrtf(ss), 1e-12f);
        const float v = (float)hist[pp][lane] / nrm;
        out[((size_t)a * BS + B) * 16 + mat * 8 + lane] = v;
        if (a != B)
            out[((size_t)B * BS + a) * 16 + mat * 8 + lane] = v;
    }
}

extern "C" void kernel_launch(void* const* d_in, const int* in_sizes, int n_in,
                              void* d_out, int out_size, void* d_ws, size_t ws_size,
                              hipStream_t stream) {
    const float* m1 = (const float*)d_in[0];
    const float* m2 = (const float*)d_in[1];
    float* out = (float*)d_out;

    // Workspace: granule-major fp16 array, 2*64*128*256 u16 = 8.39 MB.
    u16* hT = (u16*)d_ws;

    convert_f16_kernel<<<dim3(128, 4), 256, 0, stream>>>(m1, m2, hT);
    gram_hist_mfma<<<dim3(NBP, 2), 512, 0, stream>>>(hT, out);
}